// Round 3
// baseline (866.911 us; speedup 1.0000x reference)
//
#include <hip/hip_runtime.h>
#include <hip/hip_bf16.h>
#include <cstdint>

// LISTA: Z = eta(X@We^T + Z@S^T), 16 unrolled steps. B=16384, n=256, m=1024.
// 256x256-tile, 8 waves (2Mx4N), BK=64, 128 KiB double-buffered XOR-swizzled
// LDS, counted-vmcnt deep prefetch (4-phase lead, vmcnt(8) steady state).
// Each step computes C = [X,Z] @ [We,S]^T (K=1280, NT=20) - no fp32 B matrix.
// Round-3 changes vs round-2:
//  (a) ONE barrier per phase (was 2): stage(p) only needs all waves past the
//      barrier following the staged region's last reads; single end-of-phase
//      barrier gives that. Halves convergence points, frees cross-wave overlap.
//  (b) mfma 32x32x16 (was 16x16x32): -12% MFMA-pipe floor (m119: 8.07cyc/32k
//      vs 4.6cyc/16k FLOP), half the MFMA instruction count. Same LDS bytes.
//  (c) bf16 epilogue via per-wave LDS transpose slab -> every global store is
//      8 full 128B lines (decisive test of the 2x WRITE_SIZE inflation).

typedef __attribute__((ext_vector_type(8))) short short8;    // 8 x bf16
typedef __attribute__((ext_vector_type(16))) float f32x16;   // 32x32 mfma acc

__device__ __forceinline__ void g2lds16(const void* g, void* l) {
    __builtin_amdgcn_global_load_lds(
        (const __attribute__((address_space(1))) uint32_t*)(uintptr_t)g,
        (__attribute__((address_space(3))) uint32_t*)(uintptr_t)l,
        16, 0, 0);
}

#define VM8  asm volatile("s_waitcnt vmcnt(8)" ::: "memory")
#define VM0  asm volatile("s_waitcnt vmcnt(0)" ::: "memory")
#define NOPX ((void)0)

// A-frags: 2 m-frags (32 rows each) x 4 k-slices from A-half HH of buffer CB.
#define LOAD_A(CB, HH) do { \
    const char* ap_ = &lds[CB][0][HH][0] + arow; \
    _Pragma("unroll") \
    for (int mf_ = 0; mf_ < 2; ++mf_) { \
        af[mf_][0] = *(const short8*)(ap_ + mf_*4096 + ck0); \
        af[mf_][1] = *(const short8*)(ap_ + mf_*4096 + ck1); \
        af[mf_][2] = *(const short8*)(ap_ + mf_*4096 + ck2); \
        af[mf_][3] = *(const short8*)(ap_ + mf_*4096 + ck3); \
    } } while (0)

// B-frag: 1 n-frag (32 cols) x 4 k-slices from B-half HH of buffer CB.
#define LOAD_B(CB, HH, BF) do { \
    const char* bp_ = &lds[CB][1][HH][0] + brow; \
    BF[0] = *(const short8*)(bp_ + ck0); \
    BF[1] = *(const short8*)(bp_ + ck1); \
    BF[2] = *(const short8*)(bp_ + ck2); \
    BF[3] = *(const short8*)(bp_ + ck3); \
} while (0)

// One phase: {ds-reads | stage issue} ; lgkmcnt(0) ; 8 MFMA ; [vmcnt] ; barrier
#define PHASE(LD1, LD2, STG, QM, QN, BF, VMW) do { \
    LD1; LD2; STG; \
    asm volatile("s_waitcnt lgkmcnt(0)" ::: "memory"); \
    __builtin_amdgcn_sched_barrier(0); \
    __builtin_amdgcn_s_setprio(1); \
    _Pragma("unroll") \
    for (int mf_ = 0; mf_ < 2; ++mf_) \
    _Pragma("unroll") \
    for (int kk_ = 0; kk_ < 4; ++kk_) \
        acc[(QM)*2+mf_][(QN)] = __builtin_amdgcn_mfma_f32_32x32x16_bf16( \
            af[mf_][kk_], BF[kk_], acc[(QM)*2+mf_][(QN)], 0, 0, 0); \
    __builtin_amdgcn_s_setprio(0); \
    VMW; \
    __builtin_amdgcn_s_barrier(); \
    __builtin_amdgcn_sched_barrier(0); \
} while (0)

// Tiles 0..NTX-1 from (Ax,Wx), stride NTX*128 B; NTX.. from (Az,Wz), NTZ*128 B.
// C[i,j] = sum_k A[i,k]*W[j,k]; output eta(C) (bf16, or fp32 if LAST).
template<int NTX, int NTZ, bool LAST>
__global__ void __launch_bounds__(512, 2)
lista_step(const unsigned short* __restrict__ Ax,
           const unsigned short* __restrict__ Wx,
           const unsigned short* __restrict__ Az,
           const unsigned short* __restrict__ Wz,
           const float* __restrict__ theta,
           unsigned short* __restrict__ Zout,
           float* __restrict__ Fout)
{
    constexpr int NT  = NTX + NTZ;     // total K-tiles of 64
    constexpr int NI  = NT / 2;        // main iterations (2 K-tiles each)
    constexpr int KBX = NTX * 128;     // X/We row stride (bytes)
    constexpr int KBZ = NTZ * 128;     // Z/S  row stride (bytes)

    // [buf][A=0/B=1][half][16KB]; half = permuted 128-row group so each half
    // is read in exactly one phase (A: bit6 of row; B: bit5 of row).
    __shared__ __align__(128) char lds[2][2][2][16384];

    const int t    = threadIdx.x;      // 0..511
    const int lane = t & 63;
    const int wave = t >> 6;           // 0..7
    const int wm   = wave >> 2;        // 0..1  (M half)
    const int wn   = wave & 3;         // 0..3  (N quarter)
    const int bm   = blockIdx.x;       // 0..63
    const int bn   = blockIdx.y;       // 0..3

    const char* Xb = (const char*)Ax + (size_t)bm * 256 * KBX;
    const char* Wb = (const char*)Wx + (size_t)bn * 256 * KBX;
    const char* Zb = (const char*)Az + (size_t)bm * 256 * KBZ;
    const char* Sb = (const char*)Wz + (size_t)bn * 256 * KBZ;

    // staging: thread t, call c handles linear chunk I = c*512+t -> compacted
    // row rho = I>>3, slot = I&7, global k-chunk = slot ^ (rho&7)  (swizzle).
    const int u    = t >> 3;                       // 0..63
    const int gb16 = ((t & 7) ^ (u & 7)) << 4;     // swizzled k-chunk byte off
    const int rA0  = u;                            // A: row = rA0+64h (+128 c=1)
    const int rB0  = (u & 31) + 2 * (u & 32);      // B: row = rB0+32h (+128 c=1)

    // fragment-read constants (32x32x16: lane -> row=lane&31, k=(lane>>5)*8+e)
    const int r31  = lane & 31;
    const int l5   = lane >> 5;                    // k-half
    const int s7   = lane & 7;                     // == (compacted row)&7
    const int ck0  = ((0 + l5) ^ s7) << 4;         // kk=0 chunk byte (swizzled)
    const int ck1  = ((2 + l5) ^ s7) << 4;         // kk=1
    const int ck2  = ((4 + l5) ^ s7) << 4;         // kk=2
    const int ck3  = ((6 + l5) ^ s7) << 4;         // kk=3
    const int arow = (wm * 64 + r31) * 128;        // A compacted-row byte base
    const int brow = (wn * 32 + r31) * 128;        // B compacted-row byte base

    f32x16 acc[4][2];
#pragma unroll
    for (int i = 0; i < 4; ++i)
#pragma unroll
        for (int j = 0; j < 2; ++j)
#pragma unroll
            for (int r = 0; r < 16; ++r) acc[i][j][r] = 0.f;

    short8 af[2][4], bf0[4], bf1[4];

    auto STAGE_A = [&](int buf, int h, int kt) {
        const char* base; int kb, ko;
        if (NTZ == 0 || kt < NTX) { base = Xb; kb = KBX; ko = kt * 128; }
        else                      { base = Zb; kb = KBZ; ko = (kt - NTX) * 128; }
        char* lp = &lds[buf][0][h][0] + t * 16;
        const size_t go = (size_t)(rA0 + 64 * h) * kb + ko + gb16;
        g2lds16(base + go, lp);
        g2lds16(base + go + (size_t)128 * kb, lp + 8192);
    };
    auto STAGE_B = [&](int buf, int h, int kt) {
        const char* base; int kb, ko;
        if (NTZ == 0 || kt < NTX) { base = Wb; kb = KBX; ko = kt * 128; }
        else                      { base = Sb; kb = KBZ; ko = (kt - NTX) * 128; }
        char* lp = &lds[buf][1][h][0] + t * 16;
        const size_t go = (size_t)(rB0 + 32 * h) * kb + ko + gb16;
        g2lds16(base + go, lp);
        g2lds16(base + go + (size_t)128 * kb, lp + 8192);
    };

    // prologue: stage tile0 (buf0) + tile1 (buf1) fully; drain tile0's 8.
    STAGE_A(0, 0, 0); STAGE_B(0, 0, 0); STAGE_A(0, 1, 0); STAGE_B(0, 1, 0);
    STAGE_A(1, 0, 1); STAGE_B(1, 0, 1); STAGE_A(1, 1, 1); STAGE_B(1, 1, 1);
    VM8;
    __builtin_amdgcn_s_barrier();
    __builtin_amdgcn_sched_barrier(0);

    // main loop. Window it: compute tiles a=2it (buf0, p1-4), b=2it+1 (buf1,
    // p5-8); stage c=2it+2 into buf0 at p2-p4, d=2it+3 into buf1 at p6-p8
    // (each region staged the phase after its last ds_read). Ledger: start 8
    // outstanding (b); p2 +4, p3 +2, p4 +2 = 16; VM8 drains b's 8 (ready for
    // p5); p6-p8 +8 = 16; VM8 drains c's 8 (ready for next p1). Quadrant order
    // (0,0)->(0,1)->(1,1)->(1,0) reuses af across 2 phases, bf0 across p1/p4.
#pragma unroll 1
    for (int it = 0; it < NI - 1; ++it) {
        const int c = 2 * it + 2, d = 2 * it + 3;
        PHASE(LOAD_A(0,0), LOAD_B(0,0,bf0), NOPX,                             0,0, bf0, NOPX);
        PHASE(LOAD_B(0,1,bf1), NOPX,        (STAGE_A(0,0,c), STAGE_B(0,0,c)), 0,1, bf1, NOPX);
        PHASE(LOAD_A(0,1), NOPX,            STAGE_B(0,1,c),                   1,1, bf1, NOPX);
        PHASE(NOPX, NOPX,                   STAGE_A(0,1,c),                   1,0, bf0, VM8);
        PHASE(LOAD_A(1,0), LOAD_B(1,0,bf0), NOPX,                             0,0, bf0, NOPX);
        PHASE(LOAD_B(1,1,bf1), NOPX,        (STAGE_A(1,0,d), STAGE_B(1,0,d)), 0,1, bf1, NOPX);
        PHASE(LOAD_A(1,1), NOPX,            STAGE_B(1,1,d),                   1,1, bf1, NOPX);
        PHASE(NOPX, NOPX,                   STAGE_A(1,1,d),                   1,0, bf0, VM8);
    }
    {   // last window: no future stages; at p4 only buf1's 8 remain -> VM0.
        PHASE(LOAD_A(0,0), LOAD_B(0,0,bf0), NOPX, 0,0, bf0, NOPX);
        PHASE(LOAD_B(0,1,bf1), NOPX,        NOPX, 0,1, bf1, NOPX);
        PHASE(LOAD_A(0,1), NOPX,            NOPX, 1,1, bf1, NOPX);
        PHASE(NOPX, NOPX,                   NOPX, 1,0, bf0, VM0);
        PHASE(LOAD_A(1,0), LOAD_B(1,0,bf0), NOPX, 0,0, bf0, NOPX);
        PHASE(LOAD_B(1,1,bf1), NOPX,        NOPX, 0,1, bf1, NOPX);
        PHASE(LOAD_A(1,1), NOPX,            NOPX, 1,1, bf1, NOPX);
        PHASE(NOPX, NOPX,                   NOPX, 1,0, bf0, NOPX);
    }

    // epilogue. 32x32 C/D: col = lane&31, row = (reg&3)+8*(reg>>2)+4*(lane>>5)
    const int colb = bn * 256 + wn * 64 + r31;
    const int rowb = bm * 256 + wm * 128;
    const float th0 = theta[colb];
    const float th1 = theta[colb + 32];

    if constexpr (LAST) {
        // fp32 direct: 32 lanes x 4B = full 128B line per row-chunk.
#pragma unroll
        for (int MF = 0; MF < 4; ++MF)
#pragma unroll
        for (int reg = 0; reg < 16; ++reg) {
            const int rrow = rowb + MF * 32 + (reg & 3) + 8 * (reg >> 2) + 4 * l5;
#pragma unroll
            for (int h = 0; h < 2; ++h) {
                const float c = acc[MF][h][reg];
                const float a = fabsf(c) - (h ? th1 : th0);
                const float z = a > 0.f ? (c > 0.f ? a : -a) : 0.f;
                Fout[(size_t)rrow * 1024 + colb + h * 32] = z;
            }
        }
    } else {
        // bf16 via per-wave 16KB LDS transpose slab (XOR-swizzled, 2-way max);
        // readback row-linear -> each store = 8 rows x 128B full lines.
        char* slab = &lds[0][0][0][0] + wave * 16384;
#pragma unroll
        for (int MF = 0; MF < 4; ++MF)
#pragma unroll
        for (int h = 0; h < 2; ++h)
#pragma unroll
        for (int reg = 0; reg < 16; ++reg) {
            const int row = MF * 32 + (reg & 3) + 8 * (reg >> 2) + 4 * l5;
            const int cb  = (h * 64 + r31 * 2) ^ ((row & 7) << 4);
            const float c = acc[MF][h][reg];
            const float a = fabsf(c) - (h ? th1 : th0);
            const float z = a > 0.f ? (c > 0.f ? a : -a) : 0.f;
            __hip_bfloat16 hb = __float2bfloat16(z);
            *(unsigned short*)(slab + row * 128 + cb) = *(const unsigned short*)&hb;
        }
        __builtin_amdgcn_sched_barrier(0);
#pragma unroll
        for (int i = 0; i < 16; ++i) {
            const int r = i * 8 + (lane >> 3);
            const short8 v = *(const short8*)(slab + r * 128 + (((lane & 7) ^ (r & 7)) << 4));
            char* gp = (char*)Zout + (size_t)(rowb + r) * 2048
                     + bn * 512 + wn * 128 + (lane & 7) * 16;
            *(short8*)gp = v;
        }
    }
}

__global__ void __launch_bounds__(256)
cvt4(const float* __restrict__ s, unsigned short* __restrict__ d, int n4)
{
    const int i = blockIdx.x * blockDim.x + threadIdx.x;
    if (i < n4) {
        const float4 v = ((const float4*)s)[i];
        ushort4 o;
        __hip_bfloat16 b;
        b = __float2bfloat16(v.x); o.x = *(unsigned short*)&b;
        b = __float2bfloat16(v.y); o.y = *(unsigned short*)&b;
        b = __float2bfloat16(v.z); o.z = *(unsigned short*)&b;
        b = __float2bfloat16(v.w); o.w = *(unsigned short*)&b;
        ((ushort4*)d)[i] = o;
    }
}

extern "C" void kernel_launch(void* const* d_in, const int* in_sizes, int n_in,
                              void* d_out, int out_size, void* d_ws, size_t ws_size,
                              hipStream_t stream) {
    (void)in_sizes; (void)n_in; (void)out_size; (void)ws_size;
    const float* X     = (const float*)d_in[0];  // 16384 x 256
    const float* We    = (const float*)d_in[1];  // 1024 x 256
    const float* S     = (const float*)d_in[2];  // 1024 x 1024
    const float* theta = (const float*)d_in[3];  // 1024
    float* out = (float*)d_out;                  // 16384 x 1024 fp32

    char* ws = (char*)d_ws;
    unsigned short* S_bf  = (unsigned short*)(ws);                           //  2 MB
    unsigned short* X_bf  = (unsigned short*)(ws + (size_t)2  * 1048576);    //  8 MB
    unsigned short* We_bf = (unsigned short*)(ws + (size_t)10 * 1048576);    // 0.5 MB
    unsigned short* Za    = (unsigned short*)(ws + (size_t)11 * 1048576);    // 32 MB
    unsigned short* Zb    = (unsigned short*)(ws + (size_t)43 * 1048576);    // 32 MB (total 75 MB)

    cvt4<<<dim3(1024), dim3(256), 0, stream>>>(S,  S_bf,  1024 * 1024 / 4);
    cvt4<<<dim3(4096), dim3(256), 0, stream>>>(X,  X_bf,  16384 * 256 / 4);
    cvt4<<<dim3(256),  dim3(256), 0, stream>>>(We, We_bf, 1024 * 256 / 4);

    const dim3 grid(64, 4), blk(512);

    // Z0 = eta(X @ We^T)            (K = 256)
    lista_step<4, 0, false><<<grid, blk, 0, stream>>>(
        X_bf, We_bf, nullptr, nullptr, theta, Za, nullptr);

    // steps 1..15: Z = eta([X,Z] @ [We,S]^T)   (K = 1280), ping-pong bf16
    unsigned short* zin = Za;
    unsigned short* zout = Zb;
    for (int tstep = 1; tstep <= 15; ++tstep) {
        lista_step<4, 16, false><<<grid, blk, 0, stream>>>(
            X_bf, We_bf, zin, S_bf, theta, zout, nullptr);
        unsigned short* tmp = zin; zin = zout; zout = tmp;
    }
    // step 16: write fp32 output directly
    lista_step<4, 16, true><<<grid, blk, 0, stream>>>(
        X_bf, We_bf, zin, S_bf, theta, nullptr, out);
}

// Round 4
// 799.514 us; speedup vs baseline: 1.0843x; 1.0843x over previous
//
#include <hip/hip_runtime.h>
#include <hip/hip_bf16.h>
#include <cstdint>

// LISTA: Z = eta(X@We^T + Z@S^T), 16 unrolled steps. B=16384, n=256, m=1024.
// 256x256-tile, 8 waves (2Mx4N), BK=64, 128 KiB double-buffered LDS,
// counted-vmcnt deep prefetch (4-phase lead, vmcnt(8) steady state), one
// barrier per phase, mfma 32x32x16, LDS-transposed bf16 epilogue.
// Each step computes C = [X,Z] @ [We,S]^T (K=1280, NT=20) - no fp32 B matrix.
// Round-4 change vs round-3:
//  swizzle swz2(row) = (row ^ (row>>2)) & 7 (was row&7) on BOTH staging-source
//  and LDS-read sides. Fixes the 3.9M bank conflicts (4 extra cyc per
//  ds_read_b128): stride-8 lane groups share row&7 and l5 -> same bank group
//  under row&7; swz2 mixes row bits 2-4 so every 8-lane group (consecutive OR
//  strided) hits 8 distinct 4-bank groups. swz2 uses only row bits 0-4 ->
//  invariant to mf/wm/wn offsets (+32/+64) -> same ck constants everywhere.

typedef __attribute__((ext_vector_type(8))) short short8;    // 8 x bf16
typedef __attribute__((ext_vector_type(16))) float f32x16;   // 32x32 mfma acc

__device__ __forceinline__ void g2lds16(const void* g, void* l) {
    __builtin_amdgcn_global_load_lds(
        (const __attribute__((address_space(1))) uint32_t*)(uintptr_t)g,
        (__attribute__((address_space(3))) uint32_t*)(uintptr_t)l,
        16, 0, 0);
}

#define VM8  asm volatile("s_waitcnt vmcnt(8)" ::: "memory")
#define VM0  asm volatile("s_waitcnt vmcnt(0)" ::: "memory")
#define NOPX ((void)0)

// A-frags: 2 m-frags (32 rows each) x 4 k-slices from A-half HH of buffer CB.
#define LOAD_A(CB, HH) do { \
    const char* ap_ = &lds[CB][0][HH][0] + arow; \
    _Pragma("unroll") \
    for (int mf_ = 0; mf_ < 2; ++mf_) { \
        af[mf_][0] = *(const short8*)(ap_ + mf_*4096 + ck0); \
        af[mf_][1] = *(const short8*)(ap_ + mf_*4096 + ck1); \
        af[mf_][2] = *(const short8*)(ap_ + mf_*4096 + ck2); \
        af[mf_][3] = *(const short8*)(ap_ + mf_*4096 + ck3); \
    } } while (0)

// B-frag: 1 n-frag (32 cols) x 4 k-slices from B-half HH of buffer CB.
#define LOAD_B(CB, HH, BF) do { \
    const char* bp_ = &lds[CB][1][HH][0] + brow; \
    BF[0] = *(const short8*)(bp_ + ck0); \
    BF[1] = *(const short8*)(bp_ + ck1); \
    BF[2] = *(const short8*)(bp_ + ck2); \
    BF[3] = *(const short8*)(bp_ + ck3); \
} while (0)

// One phase: {ds-reads | stage issue} ; lgkmcnt(0) ; 8 MFMA ; [vmcnt] ; barrier
#define PHASE(LD1, LD2, STG, QM, QN, BF, VMW) do { \
    LD1; LD2; STG; \
    asm volatile("s_waitcnt lgkmcnt(0)" ::: "memory"); \
    __builtin_amdgcn_sched_barrier(0); \
    __builtin_amdgcn_s_setprio(1); \
    _Pragma("unroll") \
    for (int mf_ = 0; mf_ < 2; ++mf_) \
    _Pragma("unroll") \
    for (int kk_ = 0; kk_ < 4; ++kk_) \
        acc[(QM)*2+mf_][(QN)] = __builtin_amdgcn_mfma_f32_32x32x16_bf16( \
            af[mf_][kk_], BF[kk_], acc[(QM)*2+mf_][(QN)], 0, 0, 0); \
    __builtin_amdgcn_s_setprio(0); \
    VMW; \
    __builtin_amdgcn_s_barrier(); \
    __builtin_amdgcn_sched_barrier(0); \
} while (0)

// Tiles 0..NTX-1 from (Ax,Wx), stride NTX*128 B; NTX.. from (Az,Wz), NTZ*128 B.
// C[i,j] = sum_k A[i,k]*W[j,k]; output eta(C) (bf16, or fp32 if LAST).
template<int NTX, int NTZ, bool LAST>
__global__ void __launch_bounds__(512, 2)
lista_step(const unsigned short* __restrict__ Ax,
           const unsigned short* __restrict__ Wx,
           const unsigned short* __restrict__ Az,
           const unsigned short* __restrict__ Wz,
           const float* __restrict__ theta,
           unsigned short* __restrict__ Zout,
           float* __restrict__ Fout)
{
    constexpr int NT  = NTX + NTZ;     // total K-tiles of 64
    constexpr int NI  = NT / 2;        // main iterations (2 K-tiles each)
    constexpr int KBX = NTX * 128;     // X/We row stride (bytes)
    constexpr int KBZ = NTZ * 128;     // Z/S  row stride (bytes)

    // [buf][A=0/B=1][half][16KB]; half = permuted 128-row group so each half
    // is read in exactly one phase (A: bit6 of row; B: bit5 of row).
    __shared__ __align__(128) char lds[2][2][2][16384];

    const int t    = threadIdx.x;      // 0..511
    const int lane = t & 63;
    const int wave = t >> 6;           // 0..7
    const int wm   = wave >> 2;        // 0..1  (M half)
    const int wn   = wave & 3;         // 0..3  (N quarter)
    const int bm   = blockIdx.x;       // 0..63
    const int bn   = blockIdx.y;       // 0..3

    const char* Xb = (const char*)Ax + (size_t)bm * 256 * KBX;
    const char* Wb = (const char*)Wx + (size_t)bn * 256 * KBX;
    const char* Zb = (const char*)Az + (size_t)bm * 256 * KBZ;
    const char* Sb = (const char*)Wz + (size_t)bn * 256 * KBZ;

    // staging: thread t, call c handles linear chunk I = c*512+t -> compacted
    // row rho = I>>3, slot = I&7; slot holds global k-chunk slot ^ swz2(rho),
    // swz2(r) = (r ^ (r>>2)) & 7 (bits 0-4 only -> same for c=0/1 and all
    // +32/+64 row offsets).
    const int u    = t >> 3;                       // 0..63
    const int gb16 = ((t & 7) ^ ((u ^ (u >> 2)) & 7)) << 4;  // swizzled k-chunk
    const int rA0  = u;                            // A: row = rA0+64h (+128 c=1)
    const int rB0  = (u & 31) + 2 * (u & 32);      // B: row = rB0+32h (+128 c=1)

    // fragment-read constants (32x32x16: lane -> row=lane&31, k=(lane>>5)*8+e)
    const int r31  = lane & 31;
    const int l5   = lane >> 5;                    // k-half
    const int sw   = (r31 ^ (r31 >> 2)) & 7;       // swz2 of compacted row
    const int ck0  = ((0 + l5) ^ sw) << 4;         // kk=0 chunk byte (swizzled)
    const int ck1  = ((2 + l5) ^ sw) << 4;         // kk=1
    const int ck2  = ((4 + l5) ^ sw) << 4;         // kk=2
    const int ck3  = ((6 + l5) ^ sw) << 4;         // kk=3
    const int arow = (wm * 64 + r31) * 128;        // A compacted-row byte base
    const int brow = (wn * 32 + r31) * 128;        // B compacted-row byte base

    f32x16 acc[4][2];
#pragma unroll
    for (int i = 0; i < 4; ++i)
#pragma unroll
        for (int j = 0; j < 2; ++j)
#pragma unroll
            for (int r = 0; r < 16; ++r) acc[i][j][r] = 0.f;

    short8 af[2][4], bf0[4], bf1[4];

    auto STAGE_A = [&](int buf, int h, int kt) {
        const char* base; int kb, ko;
        if (NTZ == 0 || kt < NTX) { base = Xb; kb = KBX; ko = kt * 128; }
        else                      { base = Zb; kb = KBZ; ko = (kt - NTX) * 128; }
        char* lp = &lds[buf][0][h][0] + t * 16;
        const size_t go = (size_t)(rA0 + 64 * h) * kb + ko + gb16;
        g2lds16(base + go, lp);
        g2lds16(base + go + (size_t)128 * kb, lp + 8192);
    };
    auto STAGE_B = [&](int buf, int h, int kt) {
        const char* base; int kb, ko;
        if (NTZ == 0 || kt < NTX) { base = Wb; kb = KBX; ko = kt * 128; }
        else                      { base = Sb; kb = KBZ; ko = (kt - NTX) * 128; }
        char* lp = &lds[buf][1][h][0] + t * 16;
        const size_t go = (size_t)(rB0 + 32 * h) * kb + ko + gb16;
        g2lds16(base + go, lp);
        g2lds16(base + go + (size_t)128 * kb, lp + 8192);
    };

    // prologue: stage tile0 (buf0) + tile1 (buf1) fully; drain tile0's 8.
    STAGE_A(0, 0, 0); STAGE_B(0, 0, 0); STAGE_A(0, 1, 0); STAGE_B(0, 1, 0);
    STAGE_A(1, 0, 1); STAGE_B(1, 0, 1); STAGE_A(1, 1, 1); STAGE_B(1, 1, 1);
    VM8;
    __builtin_amdgcn_s_barrier();
    __builtin_amdgcn_sched_barrier(0);

    // main loop. Window it: compute tiles a=2it (buf0, p1-4), b=2it+1 (buf1,
    // p5-8); stage c=2it+2 into buf0 at p2-p4, d=2it+3 into buf1 at p6-p8
    // (each region staged the phase after its last ds_read). Ledger: start 8
    // outstanding (b); p2 +4, p3 +2, p4 +2 = 16; VM8 drains b's 8 (ready for
    // p5); p6-p8 +8 = 16; VM8 drains c's 8 (ready for next p1). Quadrant order
    // (0,0)->(0,1)->(1,1)->(1,0) reuses af across 2 phases, bf0 across p1/p4.
#pragma unroll 1
    for (int it = 0; it < NI - 1; ++it) {
        const int c = 2 * it + 2, d = 2 * it + 3;
        PHASE(LOAD_A(0,0), LOAD_B(0,0,bf0), NOPX,                             0,0, bf0, NOPX);
        PHASE(LOAD_B(0,1,bf1), NOPX,        (STAGE_A(0,0,c), STAGE_B(0,0,c)), 0,1, bf1, NOPX);
        PHASE(LOAD_A(0,1), NOPX,            STAGE_B(0,1,c),                   1,1, bf1, NOPX);
        PHASE(NOPX, NOPX,                   STAGE_A(0,1,c),                   1,0, bf0, VM8);
        PHASE(LOAD_A(1,0), LOAD_B(1,0,bf0), NOPX,                             0,0, bf0, NOPX);
        PHASE(LOAD_B(1,1,bf1), NOPX,        (STAGE_A(1,0,d), STAGE_B(1,0,d)), 0,1, bf1, NOPX);
        PHASE(LOAD_A(1,1), NOPX,            STAGE_B(1,1,d),                   1,1, bf1, NOPX);
        PHASE(NOPX, NOPX,                   STAGE_A(1,1,d),                   1,0, bf0, VM8);
    }
    {   // last window: no future stages; at p4 only buf1's 8 remain -> VM0.
        PHASE(LOAD_A(0,0), LOAD_B(0,0,bf0), NOPX, 0,0, bf0, NOPX);
        PHASE(LOAD_B(0,1,bf1), NOPX,        NOPX, 0,1, bf1, NOPX);
        PHASE(LOAD_A(0,1), NOPX,            NOPX, 1,1, bf1, NOPX);
        PHASE(NOPX, NOPX,                   NOPX, 1,0, bf0, VM0);
        PHASE(LOAD_A(1,0), LOAD_B(1,0,bf0), NOPX, 0,0, bf0, NOPX);
        PHASE(LOAD_B(1,1,bf1), NOPX,        NOPX, 0,1, bf1, NOPX);
        PHASE(LOAD_A(1,1), NOPX,            NOPX, 1,1, bf1, NOPX);
        PHASE(NOPX, NOPX,                   NOPX, 1,0, bf0, NOPX);
    }

    // epilogue. 32x32 C/D: col = lane&31, row = (reg&3)+8*(reg>>2)+4*(lane>>5)
    const int colb = bn * 256 + wn * 64 + r31;
    const int rowb = bm * 256 + wm * 128;
    const float th0 = theta[colb];
    const float th1 = theta[colb + 32];

    if constexpr (LAST) {
        // fp32 direct: 32 lanes x 4B = full 128B line per row-chunk.
#pragma unroll
        for (int MF = 0; MF < 4; ++MF)
#pragma unroll
        for (int reg = 0; reg < 16; ++reg) {
            const int rrow = rowb + MF * 32 + (reg & 3) + 8 * (reg >> 2) + 4 * l5;
#pragma unroll
            for (int h = 0; h < 2; ++h) {
                const float c = acc[MF][h][reg];
                const float a = fabsf(c) - (h ? th1 : th0);
                const float z = a > 0.f ? (c > 0.f ? a : -a) : 0.f;
                Fout[(size_t)rrow * 1024 + colb + h * 32] = z;
            }
        }
    } else {
        // bf16 via per-wave 16KB LDS transpose slab; readback row-linear ->
        // each global store = 8 rows x 128B full lines (no write RMW).
        char* slab = &lds[0][0][0][0] + wave * 16384;
#pragma unroll
        for (int MF = 0; MF < 4; ++MF)
#pragma unroll
        for (int h = 0; h < 2; ++h)
#pragma unroll
        for (int reg = 0; reg < 16; ++reg) {
            const int row = MF * 32 + (reg & 3) + 8 * (reg >> 2) + 4 * l5;
            const int cb  = (h * 64 + r31 * 2) ^ ((row & 7) << 4);
            const float c = acc[MF][h][reg];
            const float a = fabsf(c) - (h ? th1 : th0);
            const float z = a > 0.f ? (c > 0.f ? a : -a) : 0.f;
            __hip_bfloat16 hb = __float2bfloat16(z);
            *(unsigned short*)(slab + row * 128 + cb) = *(const unsigned short*)&hb;
        }
        __builtin_amdgcn_sched_barrier(0);
#pragma unroll
        for (int i = 0; i < 16; ++i) {
            const int r = i * 8 + (lane >> 3);
            const short8 v = *(const short8*)(slab + r * 128 + (((lane & 7) ^ (r & 7)) << 4));
            char* gp = (char*)Zout + (size_t)(rowb + r) * 2048
                     + bn * 512 + wn * 128 + (lane & 7) * 16;
            *(short8*)gp = v;
        }
    }
}

__global__ void __launch_bounds__(256)
cvt4(const float* __restrict__ s, unsigned short* __restrict__ d, int n4)
{
    const int i = blockIdx.x * blockDim.x + threadIdx.x;
    if (i < n4) {
        const float4 v = ((const float4*)s)[i];
        ushort4 o;
        __hip_bfloat16 b;
        b = __float2bfloat16(v.x); o.x = *(unsigned short*)&b;
        b = __float2bfloat16(v.y); o.y = *(unsigned short*)&b;
        b = __float2bfloat16(v.z); o.z = *(unsigned short*)&b;
        b = __float2bfloat16(v.w); o.w = *(unsigned short*)&b;
        ((ushort4*)d)[i] = o;
    }
}

extern "C" void kernel_launch(void* const* d_in, const int* in_sizes, int n_in,
                              void* d_out, int out_size, void* d_ws, size_t ws_size,
                              hipStream_t stream) {
    (void)in_sizes; (void)n_in; (void)out_size; (void)ws_size;
    const float* X     = (const float*)d_in[0];  // 16384 x 256
    const float* We    = (const float*)d_in[1];  // 1024 x 256
    const float* S     = (const float*)d_in[2];  // 1024 x 1024
    const float* theta = (const float*)d_in[3];  // 1024
    float* out = (float*)d_out;                  // 16384 x 1024 fp32

    char* ws = (char*)d_ws;
    unsigned short* S_bf  = (unsigned short*)(ws);                           //  2 MB
    unsigned short* X_bf  = (unsigned short*)(ws + (size_t)2  * 1048576);    //  8 MB
    unsigned short* We_bf = (unsigned short*)(ws + (size_t)10 * 1048576);    // 0.5 MB
    unsigned short* Za    = (unsigned short*)(ws + (size_t)11 * 1048576);    // 32 MB
    unsigned short* Zb    = (unsigned short*)(ws + (size_t)43 * 1048576);    // 32 MB (total 75 MB)

    cvt4<<<dim3(1024), dim3(256), 0, stream>>>(S,  S_bf,  1024 * 1024 / 4);
    cvt4<<<dim3(4096), dim3(256), 0, stream>>>(X,  X_bf,  16384 * 256 / 4);
    cvt4<<<dim3(256),  dim3(256), 0, stream>>>(We, We_bf, 1024 * 256 / 4);

    const dim3 grid(64, 4), blk(512);

    // Z0 = eta(X @ We^T)            (K = 256)
    lista_step<4, 0, false><<<grid, blk, 0, stream>>>(
        X_bf, We_bf, nullptr, nullptr, theta, Za, nullptr);

    // steps 1..15: Z = eta([X,Z] @ [We,S]^T)   (K = 1280), ping-pong bf16
    unsigned short* zin = Za;
    unsigned short* zout = Zb;
    for (int tstep = 1; tstep <= 15; ++tstep) {
        lista_step<4, 16, false><<<grid, blk, 0, stream>>>(
            X_bf, We_bf, zin, S_bf, theta, zout, nullptr);
        unsigned short* tmp = zin; zin = zout; zout = tmp;
    }
    // step 16: write fp32 output directly
    lista_step<4, 16, true><<<grid, blk, 0, stream>>>(
        X_bf, We_bf, zin, S_bf, theta, nullptr, out);
}